// Round 2
// baseline (777.965 us; speedup 1.0000x reference)
//
#include <hip/hip_runtime.h>
#include <math.h>

#define B_ 256
#define S_ 200
#define D_ 256
#define H_ 8
#define DH_ 32
#define BS_ (B_*S_)      // 51200 rows
#define NEL ((size_t)BS_*D_)   // 13107200

__device__ __forceinline__ float wave_reduce_sum(float v) {
#pragma unroll
  for (int o = 32; o >= 1; o >>= 1) v += __shfl_xor(v, o, 64);
  return v;
}

// ---------------- LayerNorm: one wave per row of 256 ----------------
__global__ __launch_bounds__(256) void ln_kernel(
    const float* __restrict__ x, const float* __restrict__ a,
    const float* __restrict__ b, float* __restrict__ y, int nrows) {
  int wave = threadIdx.x >> 6, lane = threadIdx.x & 63;
  int row = blockIdx.x * 4 + wave;
  if (row >= nrows) return;
  float4 v = ((const float4*)(x + (size_t)row * D_))[lane];
  float s  = v.x + v.y + v.z + v.w;
  float ss = v.x*v.x + v.y*v.y + v.z*v.z + v.w*v.w;
  s = wave_reduce_sum(s); ss = wave_reduce_sum(ss);
  float mean = s * (1.0f / D_);
  float var  = fmaxf((ss - (float)D_ * mean * mean) * (1.0f / (D_ - 1)), 0.0f);
  float inv  = 1.0f / (sqrtf(var) + 1e-6f);
  float4 av = ((const float4*)a)[lane];
  float4 bv = ((const float4*)b)[lane];
  float4 o;
  o.x = av.x * (v.x - mean) * inv + bv.x;
  o.y = av.y * (v.y - mean) * inv + bv.y;
  o.z = av.z * (v.z - mean) * inv + bv.z;
  o.w = av.w * (v.w - mean) * inv + bv.w;
  ((float4*)(y + (size_t)row * D_))[lane] = o;
}

// ---------------- row stats (mean, 1/(std+eps)) ----------------
__global__ __launch_bounds__(256) void rowstats_kernel(
    const float* __restrict__ x, float2* __restrict__ st, int nrows) {
  int wave = threadIdx.x >> 6, lane = threadIdx.x & 63;
  int row = blockIdx.x * 4 + wave;
  if (row >= nrows) return;
  float4 v = ((const float4*)(x + (size_t)row * D_))[lane];
  float s  = v.x + v.y + v.z + v.w;
  float ss = v.x*v.x + v.y*v.y + v.z*v.z + v.w*v.w;
  s = wave_reduce_sum(s); ss = wave_reduce_sum(ss);
  if (lane == 0) {
    float mean = s * (1.0f / D_);
    float var  = fmaxf((ss - (float)D_ * mean * mean) * (1.0f / (D_ - 1)), 0.0f);
    st[row] = make_float2(mean, 1.0f / (sqrtf(var) + 1e-6f));
  }
}

// ---------------- f32 GEMM: C[m,n] = sum_k A[m,k]*W[n,k] (+epilogue) ----------------
// EPI 0: out = C + bias[n] + add[m,n]
// EPI 1: A LN'd on load via stats/ga/gb; z=(C+bias[n])*sf[m%S]; out = add[m,n] + gelu(z)
template <int EPI>
__global__ __launch_bounds__(256) void gemm_kernel(
    const float* __restrict__ A, const float* __restrict__ W,
    const float* __restrict__ bias, const float* __restrict__ add,
    const float* __restrict__ sf, const float2* __restrict__ stats,
    const float* __restrict__ ga, const float* __restrict__ gb,
    float* __restrict__ out) {
  __shared__ float As[16][68];   // [k][m], padded row = 68 (16B-aligned rows, no 4-way banks)
  __shared__ float Bs[16][68];   // [k][n]
  const int m0 = blockIdx.x * 64;
  const int n0 = blockIdx.y * 64;
  const int tid = threadIdx.x;
  const int tx = tid & 15, ty = tid >> 4;
  const int lr = tid >> 2;          // 0..63: tile row for loading
  const int lc = (tid & 3) * 4;     // 0,4,8,12: k offset for loading
  float acc[4][4] = {};

  for (int k0 = 0; k0 < D_; k0 += 16) {
    float4 av = *(const float4*)(A + (size_t)(m0 + lr) * D_ + k0 + lc);
    if (EPI == 1) {
      float2 st = stats[m0 + lr];
      av.x = (av.x - st.x) * st.y * ga[k0 + lc + 0] + gb[k0 + lc + 0];
      av.y = (av.y - st.x) * st.y * ga[k0 + lc + 1] + gb[k0 + lc + 1];
      av.z = (av.z - st.x) * st.y * ga[k0 + lc + 2] + gb[k0 + lc + 2];
      av.w = (av.w - st.x) * st.y * ga[k0 + lc + 3] + gb[k0 + lc + 3];
    }
    float4 wv = *(const float4*)(W + (size_t)(n0 + lr) * D_ + k0 + lc);
    As[lc + 0][lr] = av.x; As[lc + 1][lr] = av.y;
    As[lc + 2][lr] = av.z; As[lc + 3][lr] = av.w;
    Bs[lc + 0][lr] = wv.x; Bs[lc + 1][lr] = wv.y;
    Bs[lc + 2][lr] = wv.z; Bs[lc + 3][lr] = wv.w;
    __syncthreads();
#pragma unroll
    for (int kk = 0; kk < 16; kk++) {
      const float4 a4 = *(const float4*)&As[kk][ty * 4];
      const float4 b4 = *(const float4*)&Bs[kk][tx * 4];
      const float ar[4] = {a4.x, a4.y, a4.z, a4.w};
      const float br[4] = {b4.x, b4.y, b4.z, b4.w};
#pragma unroll
      for (int i = 0; i < 4; i++)
#pragma unroll
        for (int j = 0; j < 4; j++)
          acc[i][j] = fmaf(ar[i], br[j], acc[i][j]);
    }
    __syncthreads();
  }

#pragma unroll
  for (int i = 0; i < 4; i++) {
    const int m = m0 + ty * 4 + i;
    float4 o;
    float* op = &o.x;
#pragma unroll
    for (int j = 0; j < 4; j++) {
      const int n = n0 + tx * 4 + j;
      float c = acc[i][j] + bias[n];
      if (EPI == 0) {
        c += add[(size_t)m * D_ + n];
      } else {
        const int srow = m % S_;
        float z = c * sf[srow];
        float g = 0.5f * z * (1.0f + tanhf(0.79788456080286536f * (z + 0.044715f * z * z * z)));
        c = add[(size_t)m * D_ + n] + g;
      }
      op[j] = c;
    }
    *(float4*)(out + (size_t)m * D_ + n0 + tx * 4) = o;
  }
}

// ---------------- attention: one block per (b,h), one thread per query row ----------------
__global__ __launch_bounds__(256) void attn_kernel(
    const float* __restrict__ img_n, const float* __restrict__ kk,
    const int* __restrict__ mask, const float* __restrict__ scale_attn,
    float* __restrict__ ctx) {
  __shared__ __align__(16) float K_s[S_][DH_];
  __shared__ __align__(16) float V_s[S_][DH_];
  __shared__ float Q_s[S_][DH_ + 1];
  __shared__ int   m_s[S_];
  const int b = blockIdx.x >> 3, h = blockIdx.x & 7;
  const int tid = threadIdx.x;
  const size_t base = (size_t)b * S_ * D_ + h * DH_;

  for (int t = tid; t < S_ * DH_ / 4; t += 256) {   // 1600 float4s
    int k = t >> 3, d4 = (t & 7) * 4;
    *(float4*)&K_s[k][d4] = *(const float4*)(kk    + base + (size_t)k * D_ + d4);
    *(float4*)&V_s[k][d4] = *(const float4*)(img_n + base + (size_t)k * D_ + d4);
  }
  for (int t = tid; t < S_ * DH_; t += 256) {
    int q = t >> 5, d = t & 31;
    Q_s[q][d] = img_n[base + (size_t)q * D_ + d];
  }
  if (tid < S_) m_s[tid] = mask[b * S_ + tid];
  __syncthreads();

  const int q = tid;
  float acc[DH_] = {};
  float l = 0.0f;
  if (q < S_) {
    float qr[DH_];
#pragma unroll
    for (int d = 0; d < DH_; d++) qr[d] = Q_s[q][d];
    const float scale = scale_attn[h * S_ + q] * 0.17677669529663687f; // 1/sqrt(32)
    float mmax = -1e30f;
    for (int k = 0; k < S_; k++) {
      float s = 0.0f;
#pragma unroll
      for (int d4 = 0; d4 < DH_; d4 += 4) {
        float4 kv = *(const float4*)&K_s[k][d4];
        s = fmaf(qr[d4 + 0], kv.x, s);
        s = fmaf(qr[d4 + 1], kv.y, s);
        s = fmaf(qr[d4 + 2], kv.z, s);
        s = fmaf(qr[d4 + 3], kv.w, s);
      }
      s *= scale;
      if (m_s[k] == 0) s = -1e9f;
      if (s > mmax) {                     // rare after warm-up
        float corr = __expf(mmax - s);
        l *= corr;
#pragma unroll
        for (int d = 0; d < DH_; d++) acc[d] *= corr;
        mmax = s;
      }
      float p = __expf(s - mmax);
      l += p;
#pragma unroll
      for (int d4 = 0; d4 < DH_; d4 += 4) {
        float4 vv = *(const float4*)&V_s[k][d4];
        acc[d4 + 0] = fmaf(p, vv.x, acc[d4 + 0]);
        acc[d4 + 1] = fmaf(p, vv.y, acc[d4 + 1]);
        acc[d4 + 2] = fmaf(p, vv.z, acc[d4 + 2]);
        acc[d4 + 3] = fmaf(p, vv.w, acc[d4 + 3]);
      }
    }
  }
  __syncthreads();
  if (q < S_) {
    const float invl = 1.0f / l;
#pragma unroll
    for (int d = 0; d < DH_; d++) Q_s[q][d] = acc[d] * invl;
  }
  __syncthreads();
  for (int t = tid; t < S_ * DH_; t += 256) {     // coalesced store
    int k = t >> 5, d = t & 31;
    ctx[base + (size_t)k * D_ + d] = Q_s[k][d];
  }
}

extern "C" void kernel_launch(void* const* d_in, const int* in_sizes, int n_in,
                              void* d_out, int out_size, void* d_ws, size_t ws_size,
                              hipStream_t stream) {
  const float* hidden_img   = (const float*)d_in[0];
  const float* hidden_title = (const float*)d_in[1];
  const int*   mask         = (const int*)d_in[2];
  const float* a_img   = (const float*)d_in[3];
  const float* b_img   = (const float*)d_in[4];
  const float* a_title = (const float*)d_in[5];
  const float* b_title = (const float*)d_in[6];
  const float* Wb = (const float*)d_in[7];
  const float* bb = (const float*)d_in[8];
  const float* Wo = (const float*)d_in[9];
  const float* bo = (const float*)d_in[10];
  const float* scale_attn = (const float*)d_in[11];
  const float* a_out = (const float*)d_in[12];
  const float* b_out = (const float*)d_in[13];
  const float* W1 = (const float*)d_in[14];
  const float* b1 = (const float*)d_in[15];
  const float* scale_ffn = (const float*)d_in[16];
  float* out = (float*)d_out;

  float* ws    = (float*)d_ws;
  float* img_n = ws;                 // LN(hidden_img); Q and V
  float* kkbuf = ws + NEL;           // kk = img_n + k_b; later h1
  float* tbuf  = ws + 2 * NEL;       // title_n; later ctx
  float2* stats = (float2*)(ws + 3 * NEL);

  ln_kernel<<<dim3(BS_ / 4), 256, 0, stream>>>(hidden_img,   a_img,   b_img,   img_n, BS_);
  ln_kernel<<<dim3(BS_ / 4), 256, 0, stream>>>(hidden_title, a_title, b_title, tbuf,  BS_);
  // kk = title_n @ Wb^T + bb + img_n
  gemm_kernel<0><<<dim3(800, 4), 256, 0, stream>>>(tbuf, Wb, bb, img_n,
                                                   nullptr, nullptr, nullptr, nullptr, kkbuf);
  // ctx (into tbuf)
  attn_kernel<<<dim3(B_ * H_), 256, 0, stream>>>(img_n, kkbuf, mask, scale_attn, tbuf);
  // h1 = ctx @ Wo^T + bo + hidden_img   (into kkbuf; kk is dead)
  gemm_kernel<0><<<dim3(800, 4), 256, 0, stream>>>(tbuf, Wo, bo, hidden_img,
                                                   nullptr, nullptr, nullptr, nullptr, kkbuf);
  rowstats_kernel<<<dim3(BS_ / 4), 256, 0, stream>>>(kkbuf, stats, BS_);
  // out = h1 + gelu(scale_ffn * (LN(h1) @ W1^T + b1))
  gemm_kernel<1><<<dim3(800, 4), 256, 0, stream>>>(kkbuf, W1, b1, kkbuf,
                                                   scale_ffn, stats, a_out, b_out, out);
}

// Round 3
// 404.327 us; speedup vs baseline: 1.9241x; 1.9241x over previous
//
#include <hip/hip_runtime.h>
#include <math.h>

#define B_ 256
#define S_ 200
#define D_ 256
#define H_ 8
#define DH_ 32
#define BS_ (B_*S_)            // 51200 rows
#define NEL ((size_t)BS_*D_)   // 13107200

typedef __attribute__((ext_vector_type(8))) short bhalf8;  // 8 bf16 in 4 VGPRs
typedef __attribute__((ext_vector_type(4))) float fx4;

__device__ __forceinline__ unsigned short f2bf(float f) {
  union { float f; unsigned u; } x; x.f = f;
  unsigned r = x.u + 0x7FFFu + ((x.u >> 16) & 1u);   // RNE
  return (unsigned short)(r >> 16);
}

__device__ __forceinline__ bhalf8 pack8(float4 a, float4 b) {
  bhalf8 p;
  p[0] = (short)f2bf(a.x); p[1] = (short)f2bf(a.y);
  p[2] = (short)f2bf(a.z); p[3] = (short)f2bf(a.w);
  p[4] = (short)f2bf(b.x); p[5] = (short)f2bf(b.y);
  p[6] = (short)f2bf(b.z); p[7] = (short)f2bf(b.w);
  return p;
}

__device__ __forceinline__ float wave_reduce_sum(float v) {
#pragma unroll
  for (int o = 32; o >= 1; o >>= 1) v += __shfl_xor(v, o, 64);
  return v;
}

// ---------------- LayerNorm: one wave per row of 256 ----------------
__global__ __launch_bounds__(256) void ln_kernel(
    const float* __restrict__ x, const float* __restrict__ a,
    const float* __restrict__ b, float* __restrict__ y, int nrows) {
  int wave = threadIdx.x >> 6, lane = threadIdx.x & 63;
  int row = blockIdx.x * 4 + wave;
  if (row >= nrows) return;
  float4 v = ((const float4*)(x + (size_t)row * D_))[lane];
  float s  = v.x + v.y + v.z + v.w;
  float ss = v.x*v.x + v.y*v.y + v.z*v.z + v.w*v.w;
  s = wave_reduce_sum(s); ss = wave_reduce_sum(ss);
  float mean = s * (1.0f / D_);
  float var  = fmaxf((ss - (float)D_ * mean * mean) * (1.0f / (D_ - 1)), 0.0f);
  float inv  = 1.0f / (sqrtf(var) + 1e-6f);
  float4 av = ((const float4*)a)[lane];
  float4 bv = ((const float4*)b)[lane];
  float4 o;
  o.x = av.x * (v.x - mean) * inv + bv.x;
  o.y = av.y * (v.y - mean) * inv + bv.y;
  o.z = av.z * (v.z - mean) * inv + bv.z;
  o.w = av.w * (v.w - mean) * inv + bv.w;
  ((float4*)(y + (size_t)row * D_))[lane] = o;
}

// ---------------- row stats (mean, 1/(std+eps)) ----------------
__global__ __launch_bounds__(256) void rowstats_kernel(
    const float* __restrict__ x, float2* __restrict__ st, int nrows) {
  int wave = threadIdx.x >> 6, lane = threadIdx.x & 63;
  int row = blockIdx.x * 4 + wave;
  if (row >= nrows) return;
  float4 v = ((const float4*)(x + (size_t)row * D_))[lane];
  float s  = v.x + v.y + v.z + v.w;
  float ss = v.x*v.x + v.y*v.y + v.z*v.z + v.w*v.w;
  s = wave_reduce_sum(s); ss = wave_reduce_sum(ss);
  if (lane == 0) {
    float mean = s * (1.0f / D_);
    float var  = fmaxf((ss - (float)D_ * mean * mean) * (1.0f / (D_ - 1)), 0.0f);
    st[row] = make_float2(mean, 1.0f / (sqrtf(var) + 1e-6f));
  }
}

// ---------------- bf16 MFMA GEMM: C = A @ W^T (+epilogue), M=51200 N=256 K=256 ----
// 128x128 tile, BK=32, 4 waves each 32 rows x 128 cols.
// EPI 0: out = C + bias[n] + add[m,n]
// EPI 1: A LN'd on staging via stats/ga/gb; z=(C+bias[n])*sf[m%S]; out = add + gelu(z)
template <int EPI>
__global__ __launch_bounds__(256) void gemm_mfma_kernel(
    const float* __restrict__ A, const float* __restrict__ W,
    const float* __restrict__ bias, const float* __restrict__ add,
    const float* __restrict__ sf, const float2* __restrict__ stats,
    const float* __restrict__ ga, const float* __restrict__ gb,
    float* __restrict__ out) {
  __shared__ short As[128 * 40];   // pitch 40 bf16 (80B): 2-way banks, 16B aligned rows
  __shared__ short Ws[128 * 40];
  const int tid = threadIdx.x;
  const int n0 = blockIdx.x * 128, m0 = blockIdx.y * 128;
  const int wv = tid >> 6, lane = tid & 63, g = lane >> 4, cc = lane & 15;
  fx4 acc[2][8];
#pragma unroll
  for (int i = 0; i < 2; i++)
#pragma unroll
    for (int j = 0; j < 8; j++) acc[i][j] = (fx4){0.f, 0.f, 0.f, 0.f};

  for (int k0 = 0; k0 < D_; k0 += 32) {
#pragma unroll
    for (int s = 0; s < 2; s++) {
      const int i = tid + s * 256;           // 512 chunks of 8
      const int row = i >> 2, c8 = (i & 3) * 8;
      const float* gp = A + (size_t)(m0 + row) * D_ + k0 + c8;
      float4 f0 = *(const float4*)gp, f1 = *(const float4*)(gp + 4);
      if (EPI == 1) {
        float2 stt = stats[m0 + row];
        float4 a0 = *(const float4*)(ga + k0 + c8), a1 = *(const float4*)(ga + k0 + c8 + 4);
        float4 b0 = *(const float4*)(gb + k0 + c8), b1 = *(const float4*)(gb + k0 + c8 + 4);
        f0.x = (f0.x - stt.x) * stt.y * a0.x + b0.x;
        f0.y = (f0.y - stt.x) * stt.y * a0.y + b0.y;
        f0.z = (f0.z - stt.x) * stt.y * a0.z + b0.z;
        f0.w = (f0.w - stt.x) * stt.y * a0.w + b0.w;
        f1.x = (f1.x - stt.x) * stt.y * a1.x + b1.x;
        f1.y = (f1.y - stt.x) * stt.y * a1.y + b1.y;
        f1.z = (f1.z - stt.x) * stt.y * a1.z + b1.z;
        f1.w = (f1.w - stt.x) * stt.y * a1.w + b1.w;
      }
      *(bhalf8*)&As[row * 40 + c8] = pack8(f0, f1);
      const float* wp = W + (size_t)(n0 + row) * D_ + k0 + c8;
      float4 w0 = *(const float4*)wp, w1 = *(const float4*)(wp + 4);
      *(bhalf8*)&Ws[row * 40 + c8] = pack8(w0, w1);
    }
    __syncthreads();
    bhalf8 fa0 = *(const bhalf8*)&As[(wv * 32 + cc) * 40 + g * 8];
    bhalf8 fa1 = *(const bhalf8*)&As[(wv * 32 + 16 + cc) * 40 + g * 8];
#pragma unroll
    for (int j = 0; j < 8; j++) {
      bhalf8 fb = *(const bhalf8*)&Ws[(j * 16 + cc) * 40 + g * 8];
      acc[0][j] = __builtin_amdgcn_mfma_f32_16x16x32_bf16(fa0, fb, acc[0][j], 0, 0, 0);
      acc[1][j] = __builtin_amdgcn_mfma_f32_16x16x32_bf16(fa1, fb, acc[1][j], 0, 0, 0);
    }
    __syncthreads();
  }

#pragma unroll
  for (int i = 0; i < 2; i++)
#pragma unroll
    for (int j = 0; j < 8; j++)
#pragma unroll
      for (int r = 0; r < 4; r++) {
        const int m = m0 + wv * 32 + i * 16 + 4 * g + r;
        const int n = n0 + j * 16 + cc;
        float cv = acc[i][j][r] + bias[n];
        if (EPI == 0) {
          cv += add[(size_t)m * D_ + n];
        } else {
          const int srow = m % S_;
          float z = cv * sf[srow];
          float t3 = z + 0.044715f * z * z * z;
          float gl = 0.5f * z * (1.0f + tanhf(0.79788456080286536f * t3));
          cv = add[(size_t)m * D_ + n] + gl;
        }
        out[(size_t)m * D_ + n] = cv;
      }
}

// ---------------- MFMA attention: one block per (b,h), 4 independent waves ----------
// Q=V=img_n slice, K=kk slice. Wave handles q-tiles t, t+4, t+8, (t+12).
__global__ __launch_bounds__(256) void attn_mfma_kernel(
    const float* __restrict__ img_n, const float* __restrict__ kk,
    const int* __restrict__ mask, const float* __restrict__ scale_attn,
    float* __restrict__ ctx) {
  __shared__ short K_s[208 * 40];      // [key][dh], pitch 40
  __shared__ short Vt_s[32 * 216];     // [dh][key], pitch 216
  __shared__ short P_s[4][16 * 224];   // per-wave P, pitch 224, XOR-swizzled
  __shared__ int   m_s[224];
  const int tid = threadIdx.x;
  const int b = blockIdx.x >> 3, h = blockIdx.x & 7;
  const size_t base = (size_t)b * (S_ * D_) + h * DH_;

  // stage K (bf16): 200 rows x 32
  for (int i = tid; i < 800; i += 256) {
    const int row = i >> 2, c8 = (i & 3) * 8;
    const float* gp = kk + base + (size_t)row * D_ + c8;
    float4 f0 = *(const float4*)gp, f1 = *(const float4*)(gp + 4);
    *(bhalf8*)&K_s[row * 40 + c8] = pack8(f0, f1);
  }
  // stage V^T (bf16)
  for (int i = tid; i < 1600; i += 256) {
    const int row = i >> 3, d4 = (i & 7) * 4;
    const float4 f = *(const float4*)(img_n + base + (size_t)row * D_ + d4);
    Vt_s[(d4 + 0) * 216 + row] = (short)f2bf(f.x);
    Vt_s[(d4 + 1) * 216 + row] = (short)f2bf(f.y);
    Vt_s[(d4 + 2) * 216 + row] = (short)f2bf(f.z);
    Vt_s[(d4 + 3) * 216 + row] = (short)f2bf(f.w);
  }
  // zero pads: K rows 200..207 (cols 0..31), Vt cols 200..215, mask pad
  { const int row = 200 + (tid >> 5), col = tid & 31; K_s[row * 40 + col] = 0; }
  for (int i = tid; i < 512; i += 256) { const int d = i >> 4, k = 200 + (i & 15); Vt_s[d * 216 + k] = 0; }
  if (tid < 224) m_s[tid] = (tid < S_) ? mask[b * S_ + tid] : 0;

  const int wv = tid >> 6, lane = tid & 63;
  const int g = lane >> 4, c = lane & 15;
  char* Pw = (char*)&P_s[wv][0];
  // zero P pad cols 208..223 at swizzled addresses
  {
    const int row = lane >> 2, cb = 208 + (lane & 3) * 4;
#pragma unroll
    for (int j = 0; j < 4; j++) {
      const int col = cb + j;
      *(short*)(Pw + row * 448 + ((col * 2) ^ ((row >> 2) << 4))) = 0;
    }
  }
  __syncthreads();

  const float rs32 = 0.17677669529663687f;  // 1/sqrt(32)
  const fx4 zero = {0.f, 0.f, 0.f, 0.f};
  for (int t = wv; t < 13; t += 4) {
    const int q0 = t * 16;
    // Q fragment straight from global (f32 -> bf16)
    int qr = q0 + c; if (qr > S_ - 1) qr = S_ - 1;
    const float* qp = img_n + base + (size_t)qr * D_ + g * 8;
    bhalf8 af = pack8(*(const float4*)qp, *(const float4*)(qp + 4));

    fx4 st[13];
#pragma unroll
    for (int t2 = 0; t2 < 13; t2++) {
      bhalf8 kf = *(const bhalf8*)&K_s[(t2 * 16 + c) * 40 + g * 8];
      st[t2] = __builtin_amdgcn_mfma_f32_16x16x32_bf16(af, kf, zero, 0, 0, 0);
    }
    // scale + mask + row max (rows q0+4g+r live in 16-lane col groups)
    float sc[4], mx[4], l[4];
#pragma unroll
    for (int r = 0; r < 4; r++) {
      int q = q0 + 4 * g + r; if (q > S_ - 1) q = S_ - 1;
      sc[r] = scale_attn[h * S_ + q] * rs32;
      mx[r] = -1e30f; l[r] = 0.f;
    }
#pragma unroll
    for (int t2 = 0; t2 < 13; t2++) {
      const int msk = m_s[t2 * 16 + c];
#pragma unroll
      for (int r = 0; r < 4; r++) {
        float s = (msk != 0) ? st[t2][r] * sc[r] : -1e30f;
        st[t2][r] = s;
        mx[r] = fmaxf(mx[r], s);
      }
    }
#pragma unroll
    for (int r = 0; r < 4; r++) {
      mx[r] = fmaxf(mx[r], __shfl_xor(mx[r], 1));
      mx[r] = fmaxf(mx[r], __shfl_xor(mx[r], 2));
      mx[r] = fmaxf(mx[r], __shfl_xor(mx[r], 4));
      mx[r] = fmaxf(mx[r], __shfl_xor(mx[r], 8));
    }
    // exp, denominator, P -> LDS (bf16, swizzled)
#pragma unroll
    for (int t2 = 0; t2 < 13; t2++) {
#pragma unroll
      for (int r = 0; r < 4; r++) {
        float p = __expf(st[t2][r] - mx[r]);
        l[r] += p;
        const int row = 4 * g + r;
        *(short*)(Pw + row * 448 + (((t2 * 16 + c) * 2) ^ ((row >> 2) << 4))) = (short)f2bf(p);
      }
    }
#pragma unroll
    for (int r = 0; r < 4; r++) {
      l[r] += __shfl_xor(l[r], 1);
      l[r] += __shfl_xor(l[r], 2);
      l[r] += __shfl_xor(l[r], 4);
      l[r] += __shfl_xor(l[r], 8);
    }
    // PV: O[q][d] over 7 k-chunks of 32, two 16-wide d tiles
    fx4 o0 = zero, o1 = zero;
#pragma unroll
    for (int ch = 0; ch < 7; ch++) {
      bhalf8 pf = *(const bhalf8*)(Pw + c * 448 + (((ch * 32 + g * 8) * 2) ^ ((c >> 2) << 4)));
      bhalf8 v0 = *(const bhalf8*)&Vt_s[c * 216 + ch * 32 + g * 8];
      bhalf8 v1 = *(const bhalf8*)&Vt_s[(16 + c) * 216 + ch * 32 + g * 8];
      o0 = __builtin_amdgcn_mfma_f32_16x16x32_bf16(pf, v0, o0, 0, 0, 0);
      o1 = __builtin_amdgcn_mfma_f32_16x16x32_bf16(pf, v1, o1, 0, 0, 0);
    }
#pragma unroll
    for (int r = 0; r < 4; r++) {
      const int q = q0 + 4 * g + r;
      if (q < S_) {
        const float inv = 1.0f / l[r];
        ctx[base + (size_t)q * D_ + c]      = o0[r] * inv;
        ctx[base + (size_t)q * D_ + 16 + c] = o1[r] * inv;
      }
    }
  }
}

extern "C" void kernel_launch(void* const* d_in, const int* in_sizes, int n_in,
                              void* d_out, int out_size, void* d_ws, size_t ws_size,
                              hipStream_t stream) {
  const float* hidden_img   = (const float*)d_in[0];
  const float* hidden_title = (const float*)d_in[1];
  const int*   mask         = (const int*)d_in[2];
  const float* a_img   = (const float*)d_in[3];
  const float* b_img   = (const float*)d_in[4];
  const float* a_title = (const float*)d_in[5];
  const float* b_title = (const float*)d_in[6];
  const float* Wb = (const float*)d_in[7];
  const float* bb = (const float*)d_in[8];
  const float* Wo = (const float*)d_in[9];
  const float* bo = (const float*)d_in[10];
  const float* scale_attn = (const float*)d_in[11];
  const float* a_out = (const float*)d_in[12];
  const float* b_out = (const float*)d_in[13];
  const float* W1 = (const float*)d_in[14];
  const float* b1 = (const float*)d_in[15];
  const float* scale_ffn = (const float*)d_in[16];
  float* out = (float*)d_out;

  float* ws    = (float*)d_ws;
  float* img_n = ws;                 // LN(hidden_img): Q and V
  float* kkbuf = ws + NEL;           // kk = img_n + k_b; later h1
  float* tbuf  = ws + 2 * NEL;       // title_n; later ctx
  float2* stats = (float2*)(ws + 3 * NEL);

  ln_kernel<<<dim3(BS_ / 4), 256, 0, stream>>>(hidden_img,   a_img,   b_img,   img_n, BS_);
  ln_kernel<<<dim3(BS_ / 4), 256, 0, stream>>>(hidden_title, a_title, b_title, tbuf,  BS_);
  // kk = title_n @ Wb^T + bb + img_n
  gemm_mfma_kernel<0><<<dim3(2, 400), 256, 0, stream>>>(tbuf, Wb, bb, img_n,
                                                        nullptr, nullptr, nullptr, nullptr, kkbuf);
  // ctx (into tbuf)
  attn_mfma_kernel<<<dim3(B_ * H_), 256, 0, stream>>>(img_n, kkbuf, mask, scale_attn, tbuf);
  // h1 = ctx @ Wo^T + bo + hidden_img   (into kkbuf)
  gemm_mfma_kernel<0><<<dim3(2, 400), 256, 0, stream>>>(tbuf, Wo, bo, hidden_img,
                                                        nullptr, nullptr, nullptr, nullptr, kkbuf);
  rowstats_kernel<<<dim3(BS_ / 4), 256, 0, stream>>>(kkbuf, stats, BS_);
  // out = h1 + gelu(scale_ffn * (LN(h1) @ W1^T + b1))
  gemm_mfma_kernel<1><<<dim3(2, 400), 256, 0, stream>>>(kkbuf, W1, b1, kkbuf,
                                                        scale_ffn, stats, a_out, b_out, out);
}

// Round 4
// 397.710 us; speedup vs baseline: 1.9561x; 1.0166x over previous
//
#include <hip/hip_runtime.h>
#include <math.h>

#define B_ 256
#define S_ 200
#define D_ 256
#define H_ 8
#define DH_ 32
#define BS_ (B_*S_)            // 51200 rows
#define NEL ((size_t)BS_*D_)   // 13107200

typedef __attribute__((ext_vector_type(8))) short bhalf8;  // 8 bf16 in 4 VGPRs
typedef __attribute__((ext_vector_type(4))) float fx4;

__device__ __forceinline__ unsigned short f2bf(float f) {
  union { float f; unsigned u; } x; x.f = f;
  unsigned r = x.u + 0x7FFFu + ((x.u >> 16) & 1u);   // RNE
  return (unsigned short)(r >> 16);
}
__device__ __forceinline__ float bf2f(unsigned short h) {
  union { unsigned u; float f; } x; x.u = ((unsigned)h) << 16; return x.f;
}
__device__ __forceinline__ bhalf8 pack8(float4 a, float4 b) {
  bhalf8 p;
  p[0] = (short)f2bf(a.x); p[1] = (short)f2bf(a.y);
  p[2] = (short)f2bf(a.z); p[3] = (short)f2bf(a.w);
  p[4] = (short)f2bf(b.x); p[5] = (short)f2bf(b.y);
  p[6] = (short)f2bf(b.z); p[7] = (short)f2bf(b.w);
  return p;
}
__device__ __forceinline__ float wave_reduce_sum(float v) {
#pragma unroll
  for (int o = 32; o >= 1; o >>= 1) v += __shfl_xor(v, o, 64);
  return v;
}

// ---------------- weight f32 -> bf16 convert (Wb|Wo|W1 concatenated) ----------------
__global__ __launch_bounds__(256) void conv_w_kernel(
    const float* __restrict__ Wb, const float* __restrict__ Wo,
    const float* __restrict__ W1, short* __restrict__ dst) {
  const int t = blockIdx.x * 256 + threadIdx.x;      // 24576 threads, 8 elems each
  const int w = t >> 13, r = (t & 8191) * 8;
  const float* src = (w == 0) ? Wb : ((w == 1) ? Wo : W1);
  float4 f0 = *(const float4*)(src + r), f1 = *(const float4*)(src + r + 4);
  *(bhalf8*)(dst + (w << 16) + r) = pack8(f0, f1);
}

// ---------------- LayerNorm (both tensors), bf16 out: one wave per row ----------------
__global__ __launch_bounds__(256) void ln2_kernel(
    const float* __restrict__ ximg, const float* __restrict__ xtit,
    const float* __restrict__ a_img, const float* __restrict__ b_img,
    const float* __restrict__ a_tit, const float* __restrict__ b_tit,
    short* __restrict__ yimg, short* __restrict__ ytit) {
  const int wave = threadIdx.x >> 6, lane = threadIdx.x & 63;
  const int second = (blockIdx.x >= BS_ / 4) ? 1 : 0;
  const int row = (blockIdx.x - second * (BS_ / 4)) * 4 + wave;
  const float* x = second ? xtit : ximg;
  const float* a = second ? a_tit : a_img;
  const float* b = second ? b_tit : b_img;
  short* y = second ? ytit : yimg;
  float4 v = ((const float4*)(x + (size_t)row * D_))[lane];
  float s  = v.x + v.y + v.z + v.w;
  float ss = v.x*v.x + v.y*v.y + v.z*v.z + v.w*v.w;
  s = wave_reduce_sum(s); ss = wave_reduce_sum(ss);
  float mean = s * (1.0f / D_);
  float var  = fmaxf((ss - (float)D_ * mean * mean) * (1.0f / (D_ - 1)), 0.0f);
  float inv  = 1.0f / (sqrtf(var) + 1e-6f);
  float4 av = ((const float4*)a)[lane];
  float4 bv = ((const float4*)b)[lane];
  ushort4 o;
  o.x = f2bf(av.x * (v.x - mean) * inv + bv.x);
  o.y = f2bf(av.y * (v.y - mean) * inv + bv.y);
  o.z = f2bf(av.z * (v.z - mean) * inv + bv.z);
  o.w = f2bf(av.w * (v.w - mean) * inv + bv.w);
  *(ushort4*)(y + (size_t)row * D_ + lane * 4) = o;
}

// ---------------- bf16 MFMA GEMM: C = A @ W^T, full-width 256-row tiles ----------------
// 8 waves x 32 rows; whole W (256x256 bf16) staged in LDS once, pitch 260.
// A-fragments loaded direct global->VGPR with one-step prefetch (no K-loop barrier).
// EPI 0: kk = C + bias[n] + addb[m,n](bf16); write bf16
// EPI 1: h1 = C + bias[n] + addf[m,n](f32); write h1 f32 + fused-LN h1n bf16 (ga/gb)
// EPI 2: z = (C + bias[n]) * sf[m%S]; out = addf[m,n] + gelu(z); write f32
template <int EPI>
__global__ __launch_bounds__(512, 2) void gemm_k(
    const short* __restrict__ A, const short* __restrict__ W,
    const float* __restrict__ bias,
    const short* __restrict__ addb,
    const float* __restrict__ addf,
    const float* __restrict__ ga, const float* __restrict__ gb,
    const float* __restrict__ sf,
    short* __restrict__ outb, float* __restrict__ outf) {
  __shared__ short Ws[256 * 260];
  const int tid = threadIdx.x;
  // stage whole weight: 8192 16B-chunks
  for (int cid = tid; cid < 8192; cid += 512) {
    const int row = cid >> 5, ch = cid & 31;
    *(bhalf8*)&Ws[row * 260 + ch * 8] = *(const bhalf8*)(W + row * 256 + ch * 8);
  }
  __syncthreads();

  const int wv = tid >> 6, lane = tid & 63, g = lane >> 4, cc = lane & 15;
  const int mrow0 = blockIdx.x * 256 + wv * 32;
  fx4 acc[2][16];
#pragma unroll
  for (int i = 0; i < 2; i++)
#pragma unroll
    for (int j = 0; j < 16; j++) acc[i][j] = (fx4){0.f, 0.f, 0.f, 0.f};

  bhalf8 a0 = *(const bhalf8*)(A + (size_t)(mrow0 + cc) * D_ + g * 8);
  bhalf8 a1 = *(const bhalf8*)(A + (size_t)(mrow0 + 16 + cc) * D_ + g * 8);
#pragma unroll
  for (int kc = 0; kc < 8; kc++) {
    bhalf8 n0, n1;
    if (kc < 7) {
      n0 = *(const bhalf8*)(A + (size_t)(mrow0 + cc) * D_ + (kc + 1) * 32 + g * 8);
      n1 = *(const bhalf8*)(A + (size_t)(mrow0 + 16 + cc) * D_ + (kc + 1) * 32 + g * 8);
    }
#pragma unroll
    for (int j = 0; j < 16; j++) {
      bhalf8 fb = *(const bhalf8*)&Ws[(j * 16 + cc) * 260 + kc * 32 + g * 8];
      acc[0][j] = __builtin_amdgcn_mfma_f32_16x16x32_bf16(a0, fb, acc[0][j], 0, 0, 0);
      acc[1][j] = __builtin_amdgcn_mfma_f32_16x16x32_bf16(a1, fb, acc[1][j], 0, 0, 0);
    }
    a0 = n0; a1 = n1;
  }

  float bias_r[16];
#pragma unroll
  for (int j = 0; j < 16; j++) bias_r[j] = bias[j * 16 + cc];

  if (EPI == 0) {
#pragma unroll
    for (int i = 0; i < 2; i++)
#pragma unroll
      for (int r = 0; r < 4; r++) {
        const size_t m = mrow0 + i * 16 + 4 * g + r;
#pragma unroll
        for (int j = 0; j < 16; j++) {
          const int n = j * 16 + cc;
          float v = acc[i][j][r] + bias_r[j] + bf2f((unsigned short)addb[m * D_ + n]);
          outb[m * D_ + n] = (short)f2bf(v);
        }
      }
  } else if (EPI == 1) {
    float ga_r[16], gb_r[16];
#pragma unroll
    for (int j = 0; j < 16; j++) { ga_r[j] = ga[j * 16 + cc]; gb_r[j] = gb[j * 16 + cc]; }
#pragma unroll
    for (int i = 0; i < 2; i++)
#pragma unroll
      for (int r = 0; r < 4; r++) {
        const size_t m = mrow0 + i * 16 + 4 * g + r;
        float s = 0.f, ss = 0.f;
#pragma unroll
        for (int j = 0; j < 16; j++) {
          const int n = j * 16 + cc;
          float v = acc[i][j][r] + bias_r[j] + addf[m * D_ + n];
          outf[m * D_ + n] = v;
          acc[i][j][r] = v;
          s += v; ss += v * v;
        }
        s  += __shfl_xor(s, 1);  s += __shfl_xor(s, 2);  s += __shfl_xor(s, 4);  s += __shfl_xor(s, 8);
        ss += __shfl_xor(ss, 1); ss += __shfl_xor(ss, 2); ss += __shfl_xor(ss, 4); ss += __shfl_xor(ss, 8);
        const float mean = s * (1.0f / D_);
        const float var  = fmaxf((ss * (1.0f / D_) - mean * mean) * ((float)D_ / (D_ - 1)), 0.0f);
        const float inv  = 1.0f / (sqrtf(var) + 1e-6f);
#pragma unroll
        for (int j = 0; j < 16; j++) {
          const int n = j * 16 + cc;
          float h = (acc[i][j][r] - mean) * inv * ga_r[j] + gb_r[j];
          outb[m * D_ + n] = (short)f2bf(h);
        }
      }
  } else {
#pragma unroll
    for (int i = 0; i < 2; i++)
#pragma unroll
      for (int r = 0; r < 4; r++) {
        const size_t m = mrow0 + i * 16 + 4 * g + r;
        const float sfr = sf[(int)(m % S_)];
#pragma unroll
        for (int j = 0; j < 16; j++) {
          const int n = j * 16 + cc;
          float z = (acc[i][j][r] + bias_r[j]) * sfr;
          float gl = 0.5f * z * (1.0f + tanhf(0.79788456080286536f * (z + 0.044715f * z * z * z)));
          outf[m * D_ + n] = addf[m * D_ + n] + gl;
        }
      }
  }
}

// ---------------- MFMA attention: one block per (b,h), 4 independent waves ----------
__global__ __launch_bounds__(256) void attn_mfma_kernel(
    const short* __restrict__ imgb, const short* __restrict__ kkb,
    const int* __restrict__ mask, const float* __restrict__ scale_attn,
    short* __restrict__ ctxb) {
  __shared__ short K_s[208 * 40];      // [key][dh], pitch 40 (2-way banks)
  __shared__ short Vt_s[32 * 232];     // [dh][key], pitch 232 (464B: 2-way)
  __shared__ short P_s[4][16 * 232];   // per-wave P, pitch 232 (456B? no: 464B)
  __shared__ int   m_s[224];
  const int tid = threadIdx.x;
  const int b = blockIdx.x >> 3, h = blockIdx.x & 7;
  const size_t base2 = (size_t)(b * S_) * D_ + h * DH_;   // in bf16 elems

  // stage K (bf16 copy): 200 rows x 4 chunks of 16B
  for (int i = tid; i < 800; i += 256) {
    const int row = i >> 2, ch = i & 3;
    *(bhalf8*)&K_s[row * 40 + ch * 8] = *(const bhalf8*)(kkb + base2 + (size_t)row * D_ + ch * 8);
  }
  // stage V^T: row-pairs packed as dwords
  for (int t = tid; t < 400; t += 256) {
    const int p = t >> 2, ch = t & 3;                      // rows 2p,2p+1; d-offset ch*8
    bhalf8 lo = *(const bhalf8*)(imgb + base2 + (size_t)(2 * p) * D_ + ch * 8);
    bhalf8 hi = *(const bhalf8*)(imgb + base2 + (size_t)(2 * p + 1) * D_ + ch * 8);
#pragma unroll
    for (int u = 0; u < 8; u++) {
      unsigned dw = (unsigned)(unsigned short)lo[u] | ((unsigned)(unsigned short)hi[u] << 16);
      *(unsigned*)&Vt_s[(ch * 8 + u) * 232 + 2 * p] = dw;
    }
  }
  // zero pads
  { const int row = 200 + (tid >> 5), col = tid & 31; K_s[row * 40 + col] = 0; }          // K rows 200..207
  { const int row = tid >> 3, k0 = 200 + (tid & 7) * 4;                                   // Vt k 200..231
    *(unsigned long long*)&Vt_s[row * 232 + k0] = 0ULL; }
  if (tid < 224) m_s[tid] = (tid < S_) ? mask[b * S_ + tid] : 0;

  const int wv = tid >> 6, lane = tid & 63;
  const int g = lane >> 4, c = lane & 15;
  short* Pw = &P_s[wv][0];
  { const int row = lane >> 2, colq = lane & 3;                                           // P cols 208..223
    *(unsigned long long*)&Pw[row * 232 + 208 + colq * 4] = 0ULL; }
  __syncthreads();

  const float rs32 = 0.17677669529663687f;  // 1/sqrt(32)
  const fx4 zero = {0.f, 0.f, 0.f, 0.f};
  for (int t = wv; t < 13; t += 4) {
    const int q0 = t * 16;
    int qr = q0 + c; if (qr > S_ - 1) qr = S_ - 1;
    bhalf8 af = *(const bhalf8*)(imgb + base2 + (size_t)qr * D_ + g * 8);

    fx4 st[13];
    __builtin_amdgcn_s_setprio(1);
#pragma unroll
    for (int t2 = 0; t2 < 13; t2++) {
      bhalf8 kf = *(const bhalf8*)&K_s[(t2 * 16 + c) * 40 + g * 8];
      st[t2] = __builtin_amdgcn_mfma_f32_16x16x32_bf16(af, kf, zero, 0, 0, 0);
    }
    __builtin_amdgcn_s_setprio(0);
    // scale + mask + row max (rows q0+4g+r; key = t2*16 + c)
    float sc[4], mx[4], l[4];
#pragma unroll
    for (int r = 0; r < 4; r++) {
      int q = q0 + 4 * g + r; if (q > S_ - 1) q = S_ - 1;
      sc[r] = scale_attn[h * S_ + q] * rs32;
      mx[r] = -1e30f; l[r] = 0.f;
    }
#pragma unroll
    for (int t2 = 0; t2 < 13; t2++) {
      const int msk = m_s[t2 * 16 + c];
#pragma unroll
      for (int r = 0; r < 4; r++) {
        float s = (msk != 0) ? st[t2][r] * sc[r] : -1e30f;
        st[t2][r] = s;
        mx[r] = fmaxf(mx[r], s);
      }
    }
#pragma unroll
    for (int r = 0; r < 4; r++) {
      mx[r] = fmaxf(mx[r], __shfl_xor(mx[r], 1));
      mx[r] = fmaxf(mx[r], __shfl_xor(mx[r], 2));
      mx[r] = fmaxf(mx[r], __shfl_xor(mx[r], 4));
      mx[r] = fmaxf(mx[r], __shfl_xor(mx[r], 8));
    }
#pragma unroll
    for (int t2 = 0; t2 < 13; t2++) {
#pragma unroll
      for (int r = 0; r < 4; r++) {
        float p = __expf(st[t2][r] - mx[r]);
        l[r] += p;
        Pw[(4 * g + r) * 232 + t2 * 16 + c] = (short)f2bf(p);
      }
    }
#pragma unroll
    for (int r = 0; r < 4; r++) {
      l[r] += __shfl_xor(l[r], 1);
      l[r] += __shfl_xor(l[r], 2);
      l[r] += __shfl_xor(l[r], 4);
      l[r] += __shfl_xor(l[r], 8);
    }
    // PV over 7 k-chunks of 32
    fx4 o0 = zero, o1 = zero;
    __builtin_amdgcn_s_setprio(1);
#pragma unroll
    for (int ch = 0; ch < 7; ch++) {
      bhalf8 pf = *(const bhalf8*)&Pw[c * 232 + ch * 32 + g * 8];
      bhalf8 v0 = *(const bhalf8*)&Vt_s[c * 232 + ch * 32 + g * 8];
      bhalf8 v1 = *(const bhalf8*)&Vt_s[(16 + c) * 232 + ch * 32 + g * 8];
      o0 = __builtin_amdgcn_mfma_f32_16x16x32_bf16(pf, v0, o0, 0, 0, 0);
      o1 = __builtin_amdgcn_mfma_f32_16x16x32_bf16(pf, v1, o1, 0, 0, 0);
    }
    __builtin_amdgcn_s_setprio(0);
#pragma unroll
    for (int r = 0; r < 4; r++) {
      const int q = q0 + 4 * g + r;
      if (q < S_) {
        const float inv = 1.0f / l[r];
        ctxb[base2 + (size_t)q * D_ + c]      = (short)f2bf(o0[r] * inv);
        ctxb[base2 + (size_t)q * D_ + 16 + c] = (short)f2bf(o1[r] * inv);
      }
    }
  }
}

extern "C" void kernel_launch(void* const* d_in, const int* in_sizes, int n_in,
                              void* d_out, int out_size, void* d_ws, size_t ws_size,
                              hipStream_t stream) {
  const float* hidden_img   = (const float*)d_in[0];
  const float* hidden_title = (const float*)d_in[1];
  const int*   mask         = (const int*)d_in[2];
  const float* a_img   = (const float*)d_in[3];
  const float* b_img   = (const float*)d_in[4];
  const float* a_title = (const float*)d_in[5];
  const float* b_title = (const float*)d_in[6];
  const float* Wb = (const float*)d_in[7];
  const float* bb = (const float*)d_in[8];
  const float* Wo = (const float*)d_in[9];
  const float* bo = (const float*)d_in[10];
  const float* scale_attn = (const float*)d_in[11];
  const float* a_out = (const float*)d_in[12];
  const float* b_out = (const float*)d_in[13];
  const float* W1 = (const float*)d_in[14];
  const float* b1 = (const float*)d_in[15];
  const float* scale_ffn = (const float*)d_in[16];
  float* out = (float*)d_out;

  char* wsb = (char*)d_ws;
  short* img_nb = (short*)(wsb);                   // LN(img) bf16 (Q,V)
  short* kkb    = (short*)(wsb + 26214400);        // kk bf16 (attn K)
  short* ctxb   = (short*)(wsb + 52428800);        // title_n bf16, then ctx bf16
  float* h1     = (float*)(wsb + 78643200);        // h1 f32
  short* h1nb   = (short*)(wsb + 131072000);       // LN(h1) bf16
  short* w16    = (short*)(wsb + 157286400);       // Wb|Wo|W1 bf16

  conv_w_kernel<<<dim3(96), 256, 0, stream>>>(Wb, Wo, W1, w16);
  ln2_kernel<<<dim3(2 * BS_ / 4), 256, 0, stream>>>(hidden_img, hidden_title,
      a_img, b_img, a_title, b_title, img_nb, ctxb);
  // kk = title_n @ Wb^T + bb + img_n
  gemm_k<0><<<dim3(200), 512, 0, stream>>>(ctxb, w16, bb, img_nb,
      nullptr, nullptr, nullptr, nullptr, kkb, nullptr);
  // ctx
  attn_mfma_kernel<<<dim3(B_ * H_), 256, 0, stream>>>(img_nb, kkb, mask, scale_attn, ctxb);
  // h1 = ctx @ Wo^T + bo + hidden_img ; h1n = LN(h1) fused
  gemm_k<1><<<dim3(200), 512, 0, stream>>>(ctxb, w16 + 65536, bo, nullptr,
      hidden_img, a_out, b_out, nullptr, h1nb, h1);
  // out = h1 + gelu(scale_ffn * (h1n @ W1^T + b1))
  gemm_k<2><<<dim3(200), 512, 0, stream>>>(h1nb, w16 + 131072, b1, nullptr,
      h1, nullptr, nullptr, scale_ffn, nullptr, out);
}